// Round 3
// baseline (262.917 us; speedup 1.0000x reference)
//
#include <hip/hip_runtime.h>

typedef unsigned int u32;
typedef unsigned long long u64;

#define NBATCH 8
#define NPTS   4096
#define NQTOT  (NBATCH * NPTS)   /* 32768 */
#define KNN    16
#define NBASIS 8
#define OUTM   64
#define NSPLIT 8
#define SUBCH  (NPTS / NSPLIT)   /* 512 */
#define QPB    64
#define TKNN   (QPB * NSPLIT)    /* 512 threads = 8 waves */
#define CAP    16
#define GRP    8
#define TF1    64
#define TF2    256

// sentinel: d2 = +inf, idx = all-ones (sorts last)
#define SENT 0x7f800000ffffffffull

__device__ __forceinline__ void ce(u64& x, u64& y) {
  u64 a = x, b = y;
  bool sw = b < a;
  x = sw ? b : a;
  y = sw ? a : b;
}

// Batcher odd-even mergesort network (fully unrolled).
template <int N>
__device__ __forceinline__ void oems_sort(u64* a) {
#pragma unroll
  for (int p = 1; p < N; p <<= 1) {
#pragma unroll
    for (int k = p; k >= 1; k >>= 1) {
#pragma unroll
      for (int j = k & (p - 1); j + k < N; j += 2 * k) {
#pragma unroll
        for (int i = 0; i < k; ++i) {
          int lo = i + j, hi = i + j + k;
          if (hi < N && (lo / (2 * p)) == (hi / (2 * p)))
            ce(a[lo], a[hi]);
        }
      }
    }
  }
}

// t, a sorted asc -> t = smallest 16 of union, sorted asc.
__device__ __forceinline__ void merge16(u64 t[16], const u64 a[16]) {
  u64 m[16];
#pragma unroll
  for (int i = 0; i < 16; ++i) {
    u64 x = t[i], y = a[15 - i];
    m[i] = (x < y) ? x : y;
  }
#pragma unroll
  for (int k = 8; k >= 1; k >>= 1) {
#pragma unroll
    for (int i = 0; i < 16; ++i) {
      if ((i & k) == 0) ce(m[i], m[i | k]);
    }
  }
#pragma unroll
  for (int i = 0; i < 16; ++i) t[i] = m[i];
}

// Flush per-thread LDS append buffer into register top-16; tighten threshold.
__device__ __forceinline__ void flush_buf(u64* col, int& c, u64 t16[16],
                                          float& thr) {
  u64 a[16];
#pragma unroll
  for (int e = 0; e < 16; ++e) {
    u64 v = col[(size_t)e * TKNN];
    a[e] = (e < c) ? v : SENT;
  }
  oems_sort<16>(a);
  merge16(t16, a);
  c = 0;
  thr = __uint_as_float((u32)(t16[15] >> 32));
}

// Per (batch, 64-query group): 8 splits x 64 queries. Each thread scans 512
// candidates via scalar (wave-uniform) plane loads, keeps exact (d2,idx)-lex
// top-16 in registers; 7-way in-block merge -> final sorted top-16 to part.
__global__ __launch_bounds__(TKNN, 4) void knn_kernel(
    const float* __restrict__ Xp, const float* __restrict__ Yp,
    const float* __restrict__ Zp, u64* __restrict__ part) {
  __shared__ u64 sB[CAP * TKNN];  // 64 KB append buffer; reused for merge
  const int b = blockIdx.x;
  const int qg = blockIdx.y;
  const int tid = threadIdx.x;
  const int ql = tid & 63;
  const int sp = tid >> 6;  // split id, wave-uniform
  const int qi = qg * QPB + ql;
  const int base = b * NPTS;

  // per-lane query coords (coalesced)
  const float qx = Xp[base + qi];
  const float qy = Yp[base + qi];
  const float qz = Zp[base + qi];

  // wave-uniform candidate window -> scalar loads
  const int jbase = __builtin_amdgcn_readfirstlane(sp * SUBCH);
  const float* xs = Xp + base + jbase;
  const float* ys = Yp + base + jbase;
  const float* zs = Zp + base + jbase;
  const int sj = qi - jbase;  // self position inside window (or out of range)

  u64 t16[16];
#pragma unroll
  for (int e = 0; e < 16; ++e) t16[e] = SENT;
  int c = 0;
  float thr = __int_as_float(0x7f800000);  // +inf
  u64* col = sB + tid;

  for (int g = 0; g < SUBCH; g += GRP) {
    float cx[GRP], cy[GRP], cz[GRP];
#pragma unroll
    for (int i = 0; i < GRP; ++i) {
      cx[i] = xs[g + i];
      cy[i] = ys[g + i];
      cz[i] = zs[g + i];
    }
    if (__any(c > CAP - GRP)) flush_buf(col, c, t16, thr);
    float d2v[GRP];
    int want[GRP];
#pragma unroll
    for (int i = 0; i < GRP; ++i) {
      // Bit-exact vs reference: separate mul/add, ((x+y)+z), no FMA.
      float dx = __fadd_rn(qx, -cx[i]);
      float dy = __fadd_rn(qy, -cy[i]);
      float dz = __fadd_rn(qz, -cz[i]);
      d2v[i] = __fadd_rn(__fadd_rn(__fmul_rn(dx, dx), __fmul_rn(dy, dy)),
                         __fmul_rn(dz, dz));
      want[i] = (d2v[i] <= thr) & ((g + i) != sj);
    }
#pragma unroll
    for (int i = 0; i < GRP; ++i) {
      if (want[i]) {
        col[(size_t)c * TKNN] =
            ((u64)__float_as_uint(d2v[i]) << 32) | (u32)(jbase + g + i);
        c++;
      }
    }
  }
  flush_buf(col, c, t16, thr);

  // Cross-split merge: splits 1..7 publish, split 0 merges + writes.
  __syncthreads();  // append buffer dead; safe to repurpose
  if (sp != 0) {
#pragma unroll
    for (int e = 0; e < 16; ++e)
      sB[(size_t)(sp - 1) * (QPB * 17) + ql * 17 + e] = t16[e];  // +1 pad
  }
  __syncthreads();
  if (sp == 0) {
#pragma unroll
    for (int s = 0; s < NSPLIT - 1; ++s) {
      u64 a[16];
#pragma unroll
      for (int e = 0; e < 16; ++e)
        a[e] = sB[(size_t)s * (QPB * 17) + ql * 17 + e];
      merge16(t16, a);
    }
    u64* pb = part + base + qi;
#pragma unroll
    for (int e = 0; e < 16; ++e)
      pb[(size_t)e * NQTOT] = t16[e];  // plane-major, coalesced
  }
}

// Per-query: read sorted top-16, compute edge features, aggregate M[8][3],
// write M plane-major for feat2.
__global__ __launch_bounds__(TF1) void feat1_kernel(
    const float4* __restrict__ cpad, const u64* __restrict__ part,
    float* __restrict__ Mbuf) {
  const int gq = blockIdx.x * TF1 + threadIdx.x;
  const int b = gq >> 12;
  const float4 qc = cpad[gq];
  const float4* cb = cpad + (b << 12);

  int idxs[KNN];
  float d2s[KNN];
#pragma unroll
  for (int e = 0; e < 16; ++e) {
    u64 v = part[(size_t)e * NQTOT + gq];  // coalesced per plane
    idxs[e] = (int)(u32)v;
    d2s[e] = __uint_as_float((u32)(v >> 32));
  }
  float4 nc[KNN];
#pragma unroll
  for (int r = 0; r < KNN; ++r) nc[r] = cb[idxs[r]];  // independent gathers

  float M[NBASIS][3];
#pragma unroll
  for (int v = 0; v < NBASIS; ++v) M[v][0] = M[v][1] = M[v][2] = 0.f;

#pragma unroll
  for (int r = 0; r < KNN; ++r) {
    float rx = nc[r].x - qc.x;  // sender - receiver
    float ry = nc[r].y - qc.y;
    float rz = nc[r].z - qc.z;
    float dist = sqrtf(d2s[r]);
    float inv = 1.0f / (dist + 1e-8f);
    rx *= inv; ry *= inv; rz *= inv;
    float cut = fminf(dist * 0.1f, 1.0f);
    float g[NBASIS], s = 0.f;
#pragma unroll
    for (int v = 0; v < NBASIS; ++v) {
      float t = cut - (float)v * (1.0f / 7.0f);
      g[v] = __expf(-32.0f * t * t);  // sigma = 1/8 -> 1/(2s^2) = 32
      s += g[v];
    }
    float rs = 1.0f / s;
#pragma unroll
    for (int v = 0; v < NBASIS; ++v) {
      float rb = g[v] * rs;
      M[v][0] = fmaf(rb, rx, M[v][0]);
      M[v][1] = fmaf(rb, ry, M[v][1]);
      M[v][2] = fmaf(rb, rz, M[v][2]);
    }
  }
#pragma unroll
  for (int j = 0; j < 24; ++j)
    Mbuf[(size_t)j * NQTOT + gq] = (&M[0][0])[j];  // coalesced per plane
}

// Per-(query, w): out[q][w*3+m] = scale * sum_v W[v][w] * M[q][v][m].
// q is wave-uniform -> M reads are scalar broadcasts.
__global__ __launch_bounds__(TF2) void feat2_kernel(
    const float* __restrict__ Mbuf, const float* __restrict__ Wmat,
    float* __restrict__ out) {
  const int t = blockIdx.x * TF2 + threadIdx.x;
  const int w = t & 63;
  const int q = __builtin_amdgcn_readfirstlane(t >> 6);

  float a0 = 0.f, a1 = 0.f, a2 = 0.f;
#pragma unroll
  for (int v = 0; v < NBASIS; ++v) {
    float wc = Wmat[v * OUTM + w];  // coalesced across lanes
    float m0 = Mbuf[(size_t)(v * 3 + 0) * NQTOT + q];  // scalar
    float m1 = Mbuf[(size_t)(v * 3 + 1) * NQTOT + q];
    float m2 = Mbuf[(size_t)(v * 3 + 2) * NQTOT + q];
    a0 = fmaf(wc, m0, a0);
    a1 = fmaf(wc, m1, a1);
    a2 = fmaf(wc, m2, a2);
  }
  const float scale = 0.022097086912079608f;  // (1/sqrt(8)) / 16
  size_t o = (size_t)q * (OUTM * 3) + w * 3;
  out[o + 0] = a0 * scale;
  out[o + 1] = a1 * scale;
  out[o + 2] = a2 * scale;
}

// coords [B*N][3] -> x/y/z planes + float4 array.
__global__ void prep_kernel(const float* __restrict__ coords,
                            float* __restrict__ Xp, float* __restrict__ Yp,
                            float* __restrict__ Zp, float4* __restrict__ cpad) {
  int i = blockIdx.x * 256 + threadIdx.x;
  if (i < NQTOT) {
    float x = coords[3 * i + 0];
    float y = coords[3 * i + 1];
    float z = coords[3 * i + 2];
    Xp[i] = x; Yp[i] = y; Zp[i] = z;
    cpad[i] = make_float4(x, y, z, 0.f);
  }
}

extern "C" void kernel_launch(void* const* d_in, const int* in_sizes, int n_in,
                              void* d_out, int out_size, void* d_ws, size_t ws_size,
                              hipStream_t stream) {
  const float* coords = (const float*)d_in[0];
  const float* Wmat = (const float*)d_in[1];
  float* out = (float*)d_out;

  char* w = (char*)d_ws;
  float* Xp = (float*)(w);                         // 128 KB
  float* Yp = (float*)(w + 131072);
  float* Zp = (float*)(w + 262144);
  float4* cpad = (float4*)(w + 393216);            // 512 KB
  u64* part = (u64*)(w + 917504);                  // 4.2 MB
  float* Mbuf = (float*)(w + 917504 + (size_t)KNN * NQTOT * 8);  // 3.1 MB

  prep_kernel<<<dim3((NQTOT + 255) / 256), dim3(256), 0, stream>>>(coords, Xp, Yp, Zp, cpad);
  knn_kernel<<<dim3(NBATCH, NPTS / QPB), dim3(TKNN), 0, stream>>>(Xp, Yp, Zp, part);
  feat1_kernel<<<dim3(NQTOT / TF1), dim3(TF1), 0, stream>>>(cpad, part, Mbuf);
  feat2_kernel<<<dim3((size_t)NQTOT * OUTM / TF2), dim3(TF2), 0, stream>>>(Mbuf, Wmat, out);
}

// Round 4
// 210.373 us; speedup vs baseline: 1.2498x; 1.2498x over previous
//
#include <hip/hip_runtime.h>

typedef unsigned int u32;
typedef unsigned long long u64;

#define NBATCH 8
#define NPTS   4096
#define NQTOT  (NBATCH * NPTS)   /* 32768 */
#define KNN    16
#define NBASIS 8
#define OUTM   64
#define NSPLIT 8
#define SUBCH  (NPTS / NSPLIT)   /* 512 */
#define QPB    64
#define TKNN   (QPB * NSPLIT)    /* 512 threads = 8 waves */
#define CAP    16
#define GRP    8
#define TFE    256

// sentinel: d2 = +inf, idx = all-ones (sorts last)
#define SENT 0x7f800000ffffffffull

__device__ __forceinline__ void ce(u64& x, u64& y) {
  u64 a = x, b = y;
  bool sw = b < a;
  x = sw ? b : a;
  y = sw ? a : b;
}

// Batcher odd-even mergesort network (fully unrolled).
template <int N>
__device__ __forceinline__ void oems_sort(u64* a) {
#pragma unroll
  for (int p = 1; p < N; p <<= 1) {
#pragma unroll
    for (int k = p; k >= 1; k >>= 1) {
#pragma unroll
      for (int j = k & (p - 1); j + k < N; j += 2 * k) {
#pragma unroll
        for (int i = 0; i < k; ++i) {
          int lo = i + j, hi = i + j + k;
          if (hi < N && (lo / (2 * p)) == (hi / (2 * p)))
            ce(a[lo], a[hi]);
        }
      }
    }
  }
}

// t, a sorted asc -> t = smallest 16 of union, sorted asc.
__device__ __forceinline__ void merge16(u64 t[16], const u64 a[16]) {
  u64 m[16];
#pragma unroll
  for (int i = 0; i < 16; ++i) {
    u64 x = t[i], y = a[15 - i];
    m[i] = (x < y) ? x : y;
  }
#pragma unroll
  for (int k = 8; k >= 1; k >>= 1) {
#pragma unroll
    for (int i = 0; i < 16; ++i) {
      if ((i & k) == 0) ce(m[i], m[i | k]);
    }
  }
#pragma unroll
  for (int i = 0; i < 16; ++i) t[i] = m[i];
}

// Flush per-thread LDS append buffer into register top-16; tighten threshold.
__device__ __forceinline__ void flush_buf(u64* col, int& c, u64 t16[16],
                                          float& thr) {
  u64 a[16];
#pragma unroll
  for (int e = 0; e < 16; ++e) {
    u64 v = col[(size_t)e * TKNN];
    a[e] = (e < c) ? v : SENT;
  }
  oems_sort<16>(a);
  merge16(t16, a);
  c = 0;
  thr = __uint_as_float((u32)(t16[15] >> 32));
}

// Per (batch, 64-query group): 8 splits x 64 queries. Each thread scans 512
// candidates via wave-uniform float4 (scalar) plane loads, keeps exact
// (d2,idx)-lex top-16 in registers. Threshold seeded from the first 16
// candidates (valid upper bound on the true 16th distance) so the append
// path is cold from the start. 7-way in-block merge -> sorted top-16.
__global__ __launch_bounds__(TKNN) void knn_kernel(
    const float* __restrict__ Xp, const float* __restrict__ Yp,
    const float* __restrict__ Zp, u64* __restrict__ part) {
  __shared__ u64 sB[CAP * TKNN];  // 64 KB append buffer; reused for merge
  const int b = blockIdx.x;
  const int qg = blockIdx.y;
  const int tid = threadIdx.x;
  const int ql = tid & 63;
  const int sp = tid >> 6;  // split id, wave-uniform
  const int qi = qg * QPB + ql;
  const int base = b * NPTS;

  // per-lane query coords (coalesced)
  const float qx = Xp[base + qi];
  const float qy = Yp[base + qi];
  const float qz = Zp[base + qi];

  // wave-uniform candidate window -> scalar float4 loads
  const int jbase = __builtin_amdgcn_readfirstlane(sp * SUBCH);
  const float4* xs4 = (const float4*)(Xp + base + jbase);
  const float4* ys4 = (const float4*)(Yp + base + jbase);
  const float4* zs4 = (const float4*)(Zp + base + jbase);
  const int sj = qi - jbase;  // self position inside window (or out of range)

  // ---- Seed: exact sorted top-16 of candidates [0,16) -> warm threshold ----
  u64 t16[16];
  {
    float cx[16], cy[16], cz[16];
#pragma unroll
    for (int h = 0; h < 4; ++h) {
      float4 fx = xs4[h], fy = ys4[h], fz = zs4[h];
      cx[h * 4 + 0] = fx.x; cx[h * 4 + 1] = fx.y; cx[h * 4 + 2] = fx.z; cx[h * 4 + 3] = fx.w;
      cy[h * 4 + 0] = fy.x; cy[h * 4 + 1] = fy.y; cy[h * 4 + 2] = fy.z; cy[h * 4 + 3] = fy.w;
      cz[h * 4 + 0] = fz.x; cz[h * 4 + 1] = fz.y; cz[h * 4 + 2] = fz.z; cz[h * 4 + 3] = fz.w;
    }
#pragma unroll
    for (int i = 0; i < 16; ++i) {
      // Bit-exact vs reference: separate mul/add, ((x+y)+z), no FMA.
      float dx = __fadd_rn(qx, -cx[i]);
      float dy = __fadd_rn(qy, -cy[i]);
      float dz = __fadd_rn(qz, -cz[i]);
      float d2 = __fadd_rn(__fadd_rn(__fmul_rn(dx, dx), __fmul_rn(dy, dy)),
                           __fmul_rn(dz, dz));
      u64 v = ((u64)__float_as_uint(d2) << 32) | (u32)(jbase + i);
      t16[i] = (i == sj) ? SENT : v;
    }
    oems_sort<16>(t16);
  }
  float thr = __uint_as_float((u32)(t16[15] >> 32));
  int c = 0;
  u64* col = sB + tid;

  // ---- Main scan: candidates [16, SUBCH) in groups of 8 ----
  for (int g = 16; g < SUBCH; g += GRP) {
    float4 fx0 = xs4[(g >> 2) + 0], fx1 = xs4[(g >> 2) + 1];
    float4 fy0 = ys4[(g >> 2) + 0], fy1 = ys4[(g >> 2) + 1];
    float4 fz0 = zs4[(g >> 2) + 0], fz1 = zs4[(g >> 2) + 1];
    float cx[GRP] = {fx0.x, fx0.y, fx0.z, fx0.w, fx1.x, fx1.y, fx1.z, fx1.w};
    float cy[GRP] = {fy0.x, fy0.y, fy0.z, fy0.w, fy1.x, fy1.y, fy1.z, fy1.w};
    float cz[GRP] = {fz0.x, fz0.y, fz0.z, fz0.w, fz1.x, fz1.y, fz1.z, fz1.w};
    if (__any(c > CAP - GRP)) flush_buf(col, c, t16, thr);
    float d2v[GRP];
    int want[GRP];
#pragma unroll
    for (int i = 0; i < GRP; ++i) {
      float dx = __fadd_rn(qx, -cx[i]);
      float dy = __fadd_rn(qy, -cy[i]);
      float dz = __fadd_rn(qz, -cz[i]);
      d2v[i] = __fadd_rn(__fadd_rn(__fmul_rn(dx, dx), __fmul_rn(dy, dy)),
                         __fmul_rn(dz, dz));
      want[i] = (d2v[i] <= thr) & ((g + i) != sj);
    }
#pragma unroll
    for (int i = 0; i < GRP; ++i) {
      if (want[i]) {
        col[(size_t)c * TKNN] =
            ((u64)__float_as_uint(d2v[i]) << 32) | (u32)(jbase + g + i);
        c++;
      }
    }
  }
  flush_buf(col, c, t16, thr);

  // Cross-split merge: splits 1..7 publish, split 0 merges + writes.
  __syncthreads();  // append buffer dead; safe to repurpose
  if (sp != 0) {
#pragma unroll
    for (int e = 0; e < 16; ++e)
      sB[(size_t)(sp - 1) * (QPB * 17) + ql * 17 + e] = t16[e];  // +1 pad
  }
  __syncthreads();
  if (sp == 0) {
#pragma unroll
    for (int s = 0; s < NSPLIT - 1; ++s) {
      u64 a[16];
#pragma unroll
      for (int e = 0; e < 16; ++e)
        a[e] = sB[(size_t)s * (QPB * 17) + ql * 17 + e];
      merge16(t16, a);
    }
    u64* pb = part + base + qi;
#pragma unroll
    for (int e = 0; e < 16; ++e)
      pb[(size_t)e * NQTOT] = t16[e];  // plane-major, coalesced
  }
}

// Fused feature kernel: block = 64 queries x 4 neighbor-quarters.
// Phase 1: partial M[8][3] per (query, quarter) -> LDS reduce.
// Phase 2: lane w = tid&63 computes out[q][w*3+m] for 16 queries.
__global__ __launch_bounds__(TFE) void feat_kernel(
    const float4* __restrict__ cpad, const u64* __restrict__ part,
    const float* __restrict__ Wmat, float* __restrict__ out) {
  __shared__ float sMp[4 * QPB * 25];  // partial M, stride 25 (gcd(25,32)=1)
  __shared__ float sM[QPB * 25];       // reduced M
  const int tid = threadIdx.x;
  const int ql = tid & 63;
  const int kq = tid >> 6;
  const int gq0 = blockIdx.x * QPB;
  const int gq = gq0 + ql;
  const int b = gq >> 12;
  const float4 qc = cpad[gq];
  const float4* cb = cpad + (b << 12);

  // W column for this lane (w = ql), coalesced
  float wreg[NBASIS];
#pragma unroll
  for (int v = 0; v < NBASIS; ++v) wreg[v] = Wmat[v * OUTM + ql];

  // 4 neighbors for this (query, quarter)
  u64 pv[4];
#pragma unroll
  for (int e = 0; e < 4; ++e)
    pv[e] = part[(size_t)(kq * 4 + e) * NQTOT + gq];  // coalesced per plane

  float4 nc[4];
  float d2s[4];
#pragma unroll
  for (int e = 0; e < 4; ++e) {
    nc[e] = cb[(int)(u32)pv[e]];  // independent gathers
    d2s[e] = __uint_as_float((u32)(pv[e] >> 32));
  }

  float M[24];
#pragma unroll
  for (int j = 0; j < 24; ++j) M[j] = 0.f;
#pragma unroll
  for (int e = 0; e < 4; ++e) {
    float rx = nc[e].x - qc.x;  // sender - receiver
    float ry = nc[e].y - qc.y;
    float rz = nc[e].z - qc.z;
    float dist = sqrtf(d2s[e]);
    float inv = 1.0f / (dist + 1e-8f);
    rx *= inv; ry *= inv; rz *= inv;
    float cut = fminf(dist * 0.1f, 1.0f);
    float g[NBASIS], s = 0.f;
#pragma unroll
    for (int v = 0; v < NBASIS; ++v) {
      float t = cut - (float)v * (1.0f / 7.0f);
      g[v] = __expf(-32.0f * t * t);  // sigma = 1/8 -> 1/(2s^2) = 32
      s += g[v];
    }
    float rs = 1.0f / s;
#pragma unroll
    for (int v = 0; v < NBASIS; ++v) {
      float rb = g[v] * rs;
      M[v * 3 + 0] = fmaf(rb, rx, M[v * 3 + 0]);
      M[v * 3 + 1] = fmaf(rb, ry, M[v * 3 + 1]);
      M[v * 3 + 2] = fmaf(rb, rz, M[v * 3 + 2]);
    }
  }
#pragma unroll
  for (int j = 0; j < 24; ++j) sMp[(kq * QPB + ql) * 25 + j] = M[j];
  __syncthreads();

  // Reduce across quarters: thread (q=ql, comps kq*6..kq*6+5)
#pragma unroll
  for (int j0 = 0; j0 < 6; ++j0) {
    int j = kq * 6 + j0;
    float s = sMp[(0 * QPB + ql) * 25 + j] + sMp[(1 * QPB + ql) * 25 + j] +
              sMp[(2 * QPB + ql) * 25 + j] + sMp[(3 * QPB + ql) * 25 + j];
    sM[ql * 25 + j] = s;
  }
  __syncthreads();

  // Phase 2: lane w = ql; queries q = kq*16 + i (wave-uniform -> broadcasts)
  const float scale = 0.022097086912079608f;  // (1/sqrt(8)) / 16
#pragma unroll 4
  for (int i = 0; i < 16; ++i) {
    int q = kq * 16 + i;
    const float* mq = sM + q * 25;
    float a0 = 0.f, a1 = 0.f, a2 = 0.f;
#pragma unroll
    for (int v = 0; v < NBASIS; ++v) {
      a0 = fmaf(wreg[v], mq[v * 3 + 0], a0);
      a1 = fmaf(wreg[v], mq[v * 3 + 1], a1);
      a2 = fmaf(wreg[v], mq[v * 3 + 2], a2);
    }
    size_t o = (size_t)(gq0 + q) * (OUTM * 3) + ql * 3;
    out[o + 0] = a0 * scale;
    out[o + 1] = a1 * scale;
    out[o + 2] = a2 * scale;
  }
}

// coords [B*N][3] -> x/y/z planes + float4 array.
__global__ void prep_kernel(const float* __restrict__ coords,
                            float* __restrict__ Xp, float* __restrict__ Yp,
                            float* __restrict__ Zp, float4* __restrict__ cpad) {
  int i = blockIdx.x * 256 + threadIdx.x;
  if (i < NQTOT) {
    float x = coords[3 * i + 0];
    float y = coords[3 * i + 1];
    float z = coords[3 * i + 2];
    Xp[i] = x; Yp[i] = y; Zp[i] = z;
    cpad[i] = make_float4(x, y, z, 0.f);
  }
}

extern "C" void kernel_launch(void* const* d_in, const int* in_sizes, int n_in,
                              void* d_out, int out_size, void* d_ws, size_t ws_size,
                              hipStream_t stream) {
  const float* coords = (const float*)d_in[0];
  const float* Wmat = (const float*)d_in[1];
  float* out = (float*)d_out;

  char* w = (char*)d_ws;
  float* Xp = (float*)(w);               // 128 KB
  float* Yp = (float*)(w + 131072);
  float* Zp = (float*)(w + 262144);
  float4* cpad = (float4*)(w + 393216);  // 512 KB
  u64* part = (u64*)(w + 917504);        // 4 MB

  prep_kernel<<<dim3((NQTOT + 255) / 256), dim3(256), 0, stream>>>(coords, Xp, Yp, Zp, cpad);
  knn_kernel<<<dim3(NBATCH, NPTS / QPB), dim3(TKNN), 0, stream>>>(Xp, Yp, Zp, part);
  feat_kernel<<<dim3(NQTOT / QPB), dim3(TFE), 0, stream>>>(cpad, part, Wmat, out);
}

// Round 5
// 186.050 us; speedup vs baseline: 1.4132x; 1.1307x over previous
//
#include <hip/hip_runtime.h>

typedef unsigned int u32;
typedef unsigned long long u64;

#define NBATCH 8
#define NPTS   4096
#define NQTOT  (NBATCH * NPTS)   /* 32768 */
#define KNN    16
#define NBASIS 8
#define OUTM   64
#define NSPLIT 8
#define SUBCH  (NPTS / NSPLIT)   /* 512 */
#define QPB    64
#define TKNN   (QPB * NSPLIT)    /* 512 threads = 8 waves */
#define GRP    8
#define BUFCAP 96
#define BUFSTR 97                /* odd stride: append stores spread banks */

// sentinel: d2 = +inf, idx = all-ones (sorts last)
#define SENT 0x7f800000ffffffffull

__device__ __forceinline__ void ce(u64& x, u64& y) {
  u64 a = x, b = y;
  bool sw = b < a;
  x = sw ? b : a;
  y = sw ? a : b;
}

// Batcher odd-even mergesort network (fully unrolled).
template <int N>
__device__ __forceinline__ void oems_sort(u64* a) {
#pragma unroll
  for (int p = 1; p < N; p <<= 1) {
#pragma unroll
    for (int k = p; k >= 1; k >>= 1) {
#pragma unroll
      for (int j = k & (p - 1); j + k < N; j += 2 * k) {
#pragma unroll
        for (int i = 0; i < k; ++i) {
          int lo = i + j, hi = i + j + k;
          if (hi < N && (lo / (2 * p)) == (hi / (2 * p)))
            ce(a[lo], a[hi]);
        }
      }
    }
  }
}

// t, a sorted asc -> t = smallest 16 of union, sorted asc.
__device__ __forceinline__ void merge16(u64 t[16], const u64 a[16]) {
  u64 m[16];
#pragma unroll
  for (int i = 0; i < 16; ++i) {
    u64 x = t[i], y = a[15 - i];
    m[i] = (x < y) ? x : y;
  }
#pragma unroll
  for (int k = 8; k >= 1; k >>= 1) {
#pragma unroll
    for (int i = 0; i < 16; ++i) {
      if ((i & k) == 0) ce(m[i], m[i | k]);
    }
  }
#pragma unroll
  for (int i = 0; i < 16; ++i) t[i] = m[i];
}

// Fused kNN + tensor-product features.
// Block = 64 queries x 8 candidate-splits (512 thr). All splits prune with a
// shared per-query global threshold and funnel survivors into a shared LDS
// buffer (LDS atomics). Owner wave (split 0) digests at geometric sync points
// -> exact global top-16 without per-split lists or merge trees. Epilogue:
// owner computes M[8][3]; all waves do the W-contraction with lane = w.
__global__ __launch_bounds__(TKNN, 4) void se3_kernel(
    const float* __restrict__ Xp, const float* __restrict__ Yp,
    const float* __restrict__ Zp, const float4* __restrict__ cpad,
    const float* __restrict__ Wmat, float* __restrict__ out) {
  __shared__ u64 sBuf[QPB * BUFSTR];  // ~49.7 KB shared candidate funnel
  __shared__ u32 sCnt[QPB];
  __shared__ float sThr[QPB];
  __shared__ float sM[QPB * 25];      // M[8][3] per query, stride 25

  const int b = blockIdx.x;
  const int qg = blockIdx.y;
  const int tid = threadIdx.x;
  const int ql = tid & 63;
  const int sp = tid >> 6;  // split id, wave-uniform
  const int qi = qg * QPB + ql;
  const int base = b * NPTS;

  if (tid < QPB) sCnt[tid] = 0;

  // per-lane query coords (coalesced)
  const float qx = Xp[base + qi];
  const float qy = Yp[base + qi];
  const float qz = Zp[base + qi];

  // ---- Seed (owner wave): exact sorted top-16 of global candidates [0,16) ----
  u64 t16[16];
  if (sp == 0) {
    const float4* xs4 = (const float4*)(Xp + base);
    const float4* ys4 = (const float4*)(Yp + base);
    const float4* zs4 = (const float4*)(Zp + base);
    float cx[16], cy[16], cz[16];
#pragma unroll
    for (int h = 0; h < 4; ++h) {
      float4 fx = xs4[h], fy = ys4[h], fz = zs4[h];
      cx[h * 4 + 0] = fx.x; cx[h * 4 + 1] = fx.y; cx[h * 4 + 2] = fx.z; cx[h * 4 + 3] = fx.w;
      cy[h * 4 + 0] = fy.x; cy[h * 4 + 1] = fy.y; cy[h * 4 + 2] = fy.z; cy[h * 4 + 3] = fy.w;
      cz[h * 4 + 0] = fz.x; cz[h * 4 + 1] = fz.y; cz[h * 4 + 2] = fz.z; cz[h * 4 + 3] = fz.w;
    }
#pragma unroll
    for (int i = 0; i < 16; ++i) {
      // Bit-exact vs reference: separate mul/add, ((x+y)+z), no FMA.
      float dx = __fadd_rn(qx, -cx[i]);
      float dy = __fadd_rn(qy, -cy[i]);
      float dz = __fadd_rn(qz, -cz[i]);
      float d2 = __fadd_rn(__fadd_rn(__fmul_rn(dx, dx), __fmul_rn(dy, dy)),
                           __fmul_rn(dz, dz));
      u64 v = ((u64)__float_as_uint(d2) << 32) | (u32)i;
      t16[i] = (i == qi) ? SENT : v;
    }
    oems_sort<16>(t16);
    sThr[ql] = __uint_as_float((u32)(t16[15] >> 32));
  }
  __syncthreads();
  float thr = sThr[ql];

  // wave-uniform candidate window -> scalar float4 loads
  const int jbase = __builtin_amdgcn_readfirstlane(sp * SUBCH);
  const float4* xs4 = (const float4*)(Xp + base + jbase);
  const float4* ys4 = (const float4*)(Yp + base + jbase);
  const float4* zs4 = (const float4*)(Zp + base + jbase);

  // ---- Main scan: phases with geometric flush points ----
  int done = 0;
  for (int ph = 0; ph < 7; ++ph) {
    const int until = 1 << ph;  // 1,2,4,8,16,32,64 groups cumulative
    for (int it = done; it < until; ++it) {
      const int g = it * GRP;
      float4 fx0 = xs4[(g >> 2) + 0], fx1 = xs4[(g >> 2) + 1];
      float4 fy0 = ys4[(g >> 2) + 0], fy1 = ys4[(g >> 2) + 1];
      float4 fz0 = zs4[(g >> 2) + 0], fz1 = zs4[(g >> 2) + 1];
      float cx[GRP] = {fx0.x, fx0.y, fx0.z, fx0.w, fx1.x, fx1.y, fx1.z, fx1.w};
      float cy[GRP] = {fy0.x, fy0.y, fy0.z, fy0.w, fy1.x, fy1.y, fy1.z, fy1.w};
      float cz[GRP] = {fz0.x, fz0.y, fz0.z, fz0.w, fz1.x, fz1.y, fz1.z, fz1.w};
      float d2v[GRP];
      int want[GRP];
#pragma unroll
      for (int i = 0; i < GRP; ++i) {
        int j = jbase + g + i;
        float dx = __fadd_rn(qx, -cx[i]);
        float dy = __fadd_rn(qy, -cy[i]);
        float dz = __fadd_rn(qz, -cz[i]);
        d2v[i] = __fadd_rn(__fadd_rn(__fmul_rn(dx, dx), __fmul_rn(dy, dy)),
                           __fmul_rn(dz, dz));
        // j<16 already ingested by seed; exclude self.
        want[i] = (d2v[i] <= thr) & (j != qi) & (j >= 16);
      }
#pragma unroll
      for (int i = 0; i < GRP; ++i) {
        if (want[i]) {
          u32 slot = atomicAdd(&sCnt[ql], 1u);
          if (slot < BUFCAP)
            sBuf[ql * BUFSTR + slot] =
                ((u64)__float_as_uint(d2v[i]) << 32) | (u32)(jbase + g + i);
        }
      }
    }
    done = until;
    __syncthreads();
    if (sp == 0) {  // owner digests its query's funnel
      int n = (int)sCnt[ql];
      n = n < BUFCAP ? n : BUFCAP;
      for (int k = 0; __any(k < n); k += 16) {
        u64 a[16];
#pragma unroll
        for (int e = 0; e < 16; ++e)
          a[e] = (k + e < n) ? sBuf[ql * BUFSTR + k + e] : SENT;
        oems_sort<16>(a);
        merge16(t16, a);
      }
      sCnt[ql] = 0;
      sThr[ql] = __uint_as_float((u32)(t16[15] >> 32));
    }
    __syncthreads();
    thr = sThr[ql];
  }

  // ---- Epilogue phase 1 (owner): M[8][3] from exact top-16 ----
  if (sp == 0) {
    float M[24];
#pragma unroll
    for (int j = 0; j < 24; ++j) M[j] = 0.f;
#pragma unroll
    for (int chk = 0; chk < 4; ++chk) {
      float4 nc[4];
      float dd[4];
#pragma unroll
      for (int e = 0; e < 4; ++e) {
        u64 v = t16[chk * 4 + e];
        nc[e] = cpad[base + (int)(u32)v];  // independent gathers
        dd[e] = __uint_as_float((u32)(v >> 32));
      }
#pragma unroll
      for (int e = 0; e < 4; ++e) {
        float rx = nc[e].x - qx;  // sender - receiver
        float ry = nc[e].y - qy;
        float rz = nc[e].z - qz;
        float dist = sqrtf(dd[e]);
        float inv = 1.0f / (dist + 1e-8f);
        rx *= inv; ry *= inv; rz *= inv;
        float cut = fminf(dist * 0.1f, 1.0f);
        float g[NBASIS], s = 0.f;
#pragma unroll
        for (int v = 0; v < NBASIS; ++v) {
          float t = cut - (float)v * (1.0f / 7.0f);
          g[v] = __expf(-32.0f * t * t);  // sigma = 1/8 -> 1/(2s^2) = 32
          s += g[v];
        }
        float rs = 1.0f / s;
#pragma unroll
        for (int v = 0; v < NBASIS; ++v) {
          float rb = g[v] * rs;
          M[v * 3 + 0] = fmaf(rb, rx, M[v * 3 + 0]);
          M[v * 3 + 1] = fmaf(rb, ry, M[v * 3 + 1]);
          M[v * 3 + 2] = fmaf(rb, rz, M[v * 3 + 2]);
        }
      }
    }
#pragma unroll
    for (int j = 0; j < 24; ++j) sM[ql * 25 + j] = M[j];
  }
  __syncthreads();

  // ---- Epilogue phase 2 (all waves): out[q][w*3+m], lane w = ql ----
  float wreg[NBASIS];
#pragma unroll
  for (int v = 0; v < NBASIS; ++v) wreg[v] = Wmat[v * OUTM + ql];
  const float scale = 0.022097086912079608f;  // (1/sqrt(8)) / 16
#pragma unroll
  for (int i = 0; i < 8; ++i) {
    int q = sp * 8 + i;  // wave-uniform -> sM broadcasts
    const float* mq = sM + q * 25;
    float a0 = 0.f, a1 = 0.f, a2 = 0.f;
#pragma unroll
    for (int v = 0; v < NBASIS; ++v) {
      a0 = fmaf(wreg[v], mq[v * 3 + 0], a0);
      a1 = fmaf(wreg[v], mq[v * 3 + 1], a1);
      a2 = fmaf(wreg[v], mq[v * 3 + 2], a2);
    }
    size_t o = (size_t)(base + qg * QPB + q) * (OUTM * 3) + ql * 3;
    out[o + 0] = a0 * scale;
    out[o + 1] = a1 * scale;
    out[o + 2] = a2 * scale;
  }
}

// coords [B*N][3] -> x/y/z planes + float4 array.
__global__ void prep_kernel(const float* __restrict__ coords,
                            float* __restrict__ Xp, float* __restrict__ Yp,
                            float* __restrict__ Zp, float4* __restrict__ cpad) {
  int i = blockIdx.x * 256 + threadIdx.x;
  if (i < NQTOT) {
    float x = coords[3 * i + 0];
    float y = coords[3 * i + 1];
    float z = coords[3 * i + 2];
    Xp[i] = x; Yp[i] = y; Zp[i] = z;
    cpad[i] = make_float4(x, y, z, 0.f);
  }
}

extern "C" void kernel_launch(void* const* d_in, const int* in_sizes, int n_in,
                              void* d_out, int out_size, void* d_ws, size_t ws_size,
                              hipStream_t stream) {
  const float* coords = (const float*)d_in[0];
  const float* Wmat = (const float*)d_in[1];
  float* out = (float*)d_out;

  char* w = (char*)d_ws;
  float* Xp = (float*)(w);               // 128 KB
  float* Yp = (float*)(w + 131072);
  float* Zp = (float*)(w + 262144);
  float4* cpad = (float4*)(w + 393216);  // 512 KB

  prep_kernel<<<dim3((NQTOT + 255) / 256), dim3(256), 0, stream>>>(coords, Xp, Yp, Zp, cpad);
  se3_kernel<<<dim3(NBATCH, NPTS / QPB), dim3(TKNN), 0, stream>>>(Xp, Yp, Zp, cpad, Wmat, out);
}